// Round 13
// baseline (173.065 us; speedup 1.0000x reference)
//
#include <hip/hip_runtime.h>

#define NN 8192      // nodes
#define NG 128       // graphs
#define NF 128       // input feats
#define CL 512       // hidden dim
#define ZD 1536      // concat dim (3*512)
#define NE 262144    // edges per edge set

typedef __attribute__((ext_vector_type(8))) _Float16 half8;
typedef __attribute__((ext_vector_type(4))) float f32x4;

// ---------------- consolidated prep: cvt_h + 3x cvtT + edge-count atomics ----------------
// grid 2400 x 256: [0,512) cvt_h, [512,1536) edge counts, [1536,1600) fcW,
// [1600,2368) featW, [2368,2400) fc1W.
__global__ __launch_bounds__(256)
void prep_misc(const float* __restrict__ x, _Float16* __restrict__ xb,
               const float* __restrict__ fcW, _Float16* __restrict__ fcWt,
               const float* __restrict__ featW, _Float16* __restrict__ featWt,
               const float* __restrict__ fc1W, _Float16* __restrict__ fc1Wt,
               const int* __restrict__ ei, float* __restrict__ Acnt)
{
    const int b = blockIdx.x, tid = threadIdx.x;
    if (b < 512) {
        int i = b * 256 + tid;
        float4 a = *(const float4*)(x + (size_t)i * 8);
        float4 c = *(const float4*)(x + (size_t)i * 8 + 4);
        half8 o;
        o[0] = (_Float16)a.x; o[1] = (_Float16)a.y; o[2] = (_Float16)a.z; o[3] = (_Float16)a.w;
        o[4] = (_Float16)c.x; o[5] = (_Float16)c.y; o[6] = (_Float16)c.z; o[7] = (_Float16)c.w;
        *(half8*)(xb + (size_t)i * 8) = o;
        return;
    }
    if (b < 1536) {
        int e = (b - 512) * 256 + tid;
        int s = ei[e], d = ei[NE + e];
        int g = d >> 6;
        atomicAdd(&Acnt[(size_t)((g << 6) + (d & 63)) * 64 + (s & 63)], 1.0f);
        return;
    }
    // cvtT variants (32x8 layout from linear tid)
    const float* W; _Float16* Wt; int Kd, Nd, bx, by;
    if (b < 1600)      { int bb = b - 1536; W = fcW;   Wt = fcWt;   Kd = NF;  Nd = CL; bx = bb % 16; by = bb / 16; }
    else if (b < 2368) { int bb = b - 1600; W = featW; Wt = featWt; Kd = ZD;  Nd = CL; bx = bb % 16; by = bb / 16; }
    else               { int bb = b - 2368; W = fc1W;  Wt = fc1Wt;  Kd = 512; Nd = 64; bx = bb % 2;  by = bb / 2; }
    __shared__ float t[32][33];
    const int tx = tid & 31, ty = tid >> 5;
    const int kb = by * 32, nb = bx * 32;
    for (int i = ty; i < 32; i += 8)
        t[i][tx] = W[(size_t)(kb + i) * Nd + nb + tx];
    __syncthreads();
    for (int i = ty; i < 32; i += 8)
        Wt[(size_t)(nb + i) * Kd + kb + tx] = (_Float16)t[tx][i];
}

// ---------------- finalize adjacency: counts -> normalized, diag, f16 pre-swizzled ------
// one block per graph; deg = row-sum of count matrix.
__global__ __launch_bounds__(256)
void finalize_adj(const float* __restrict__ Acnt, _Float16* __restrict__ Ah)
{
    __shared__ float As[4096];
    __shared__ float rs[64];
    __shared__ float dinv1[64];
    const int g = blockIdx.x, tid = threadIdx.x;
    const float* Ag = Acnt + (size_t)g * 4096;
    for (int i = tid; i < 1024; i += 256)
        *(float4*)&As[i * 4] = *(const float4*)&Ag[i * 4];
    __syncthreads();
    if (tid < 64) {
        float s = 0.f;
        #pragma unroll
        for (int j = 0; j < 64; ++j) s += As[tid * 64 + j];
        float d = s + 1.0f;
        rs[tid] = rsqrtf(d);
        dinv1[tid] = 1.0f / d;
    }
    __syncthreads();
    for (int i = tid; i < 4096; i += 256) {
        int row = i >> 6, s = i & 63;
        float v = As[i] * rs[row] * rs[s];
        if (row == s) v += dinv1[row];
        Ah[(size_t)g * 4096 + (i ^ ((row & 7) << 3))] = (_Float16)v;
    }
}

// Fused BN-fold weight prep
__global__ void wprep(const float* __restrict__ W,
                      const float* __restrict__ sums, const float* __restrict__ sqs,
                      const float* __restrict__ g, const float* __restrict__ b,
                      _Float16* __restrict__ Wt, float* __restrict__ bias2,
                      int Kd, int Nd) {
    __shared__ float t[32][33];
    __shared__ float tks[32];
    int kb = blockIdx.y * 32, nb = blockIdx.x * 32;
    int tx = threadIdx.x, ty = threadIdx.y;
    for (int i = ty; i < 32; i += 8)
        t[i][tx] = W[(size_t)(kb + i) * Nd + nb + tx];
    int kc = kb + tx;
    float m = sums[kc] * (1.0f / NN);
    float var = sqs[kc] * (1.0f / NN) - m * m;
    float sc = rsqrtf(var + 1e-5f) * g[kc];
    if (ty == 0) tks[tx] = b[kc] - m * sc;
    __syncthreads();
    for (int i = ty; i < 32; i += 8)
        Wt[(size_t)(nb + i) * Kd + kb + tx] = (_Float16)(t[tx][i] * sc);
    if (ty == 0) {
        float acc = 0.f;
        #pragma unroll
        for (int i = 0; i < 32; ++i) acc = fmaf(tks[i], t[i][tx], acc);
        atomicAdd(&bias2[nb + tx], acc);
    }
}

// ---------------- f16 MFMA GEMM: C = A @ Bt^T, 128x64 tile, BK=64, XOR-swizzled LDS ---
template<int ACT, bool HASB, bool OUT16, bool STATS, bool FUSE>
__global__ __launch_bounds__(256)
void gemm_f16(const _Float16* __restrict__ A, int lda,
              const _Float16* __restrict__ Bt, int ldb,
              float* __restrict__ Cf, _Float16* __restrict__ Ch, int ldc,
              const float* __restrict__ bias, int K,
              float* __restrict__ sums, float* __restrict__ sqs,
              const _Float16* __restrict__ Ahg,
              const float* __restrict__ cb,
              _Float16* __restrict__ Zout)
{
    __shared__ __align__(16) char SMraw[FUSE ? 34816 : 24576];
    _Float16* As = (_Float16*)SMraw;              // [128][64]
    _Float16* Bs = (_Float16*)(SMraw + 16384);    // [64][64]
    const int tid = threadIdx.x;
    const int lane = tid & 63, wave = tid >> 6;
    const int wr = wave >> 1, wc = wave & 1;
    const int ntile = gridDim.x;
    const int li = blockIdx.y * ntile + blockIdx.x;
    const int x8 = li & 7, rest = li >> 3;
    const int bt = rest % ntile;
    const int bp = (rest / ntile) * 8 + x8;
    const int bm = bp * 128, bn = bt * 64;

    f32x4 acc[4][2];
    #pragma unroll
    for (int m = 0; m < 4; ++m)
        #pragma unroll
        for (int n = 0; n < 2; ++n)
            acc[m][n] = (f32x4){0.f, 0.f, 0.f, 0.f};

    const int fl = lane & 15, kh = (lane >> 4) * 8;
    const int sw = (fl & 7) << 3;

    for (int k0 = 0; k0 < K; k0 += 64) {
        #pragma unroll
        for (int j = 0; j < 4; ++j) {
            int d = wave * 2048 + j * 512 + lane * 8;
            int row = d >> 6, kk = d & 63;
            int sk = kk ^ ((row & 7) << 3);
            __builtin_amdgcn_global_load_lds(
                (const __attribute__((address_space(1))) void*)(A + (size_t)(bm + row) * lda + k0 + sk),
                (__attribute__((address_space(3))) void*)&As[wave * 2048 + j * 512], 16, 0, 0);
        }
        #pragma unroll
        for (int j = 0; j < 2; ++j) {
            int d = wave * 1024 + j * 512 + lane * 8;
            int row = d >> 6, kk = d & 63;
            int sk = kk ^ ((row & 7) << 3);
            __builtin_amdgcn_global_load_lds(
                (const __attribute__((address_space(1))) void*)(Bt + (size_t)(bn + row) * ldb + k0 + sk),
                (__attribute__((address_space(3))) void*)&Bs[wave * 1024 + j * 512], 16, 0, 0);
        }
        __syncthreads();
        #pragma unroll
        for (int kc = 0; kc < 2; ++kc) {
            int ko = (kc * 32 + kh) ^ sw;
            half8 av[4], bv[2];
            #pragma unroll
            for (int m = 0; m < 4; ++m)
                av[m] = *(const half8*)&As[(wr * 64 + m * 16 + fl) * 64 + ko];
            #pragma unroll
            for (int n = 0; n < 2; ++n)
                bv[n] = *(const half8*)&Bs[(wc * 32 + n * 16 + fl) * 64 + ko];
            #pragma unroll
            for (int m = 0; m < 4; ++m)
                #pragma unroll
                for (int n = 0; n < 2; ++n)
                    acc[m][n] = __builtin_amdgcn_mfma_f32_16x16x32_f16(av[m], bv[n], acc[m][n], 0, 0, 0);
        }
        __syncthreads();
    }

    const int orow0 = (lane >> 4) * 4;
    const int ocol  = lane & 15;

    if constexpr (!FUSE) {
        #pragma unroll
        for (int n = 0; n < 2; ++n) {
            int col = bn + wc * 32 + n * 16 + ocol;
            float bb = HASB ? bias[col] : 0.f;
            float ss = 0.f, qq = 0.f;
            #pragma unroll
            for (int m = 0; m < 4; ++m) {
                #pragma unroll
                for (int r = 0; r < 4; ++r) {
                    int rowg = bm + wr * 64 + m * 16 + orow0 + r;
                    float v = acc[m][n][r] + bb;
                    if (ACT == 2) v = v > 0.f ? v : 0.01f * v;
                    if (STATS) { ss += v; qq = fmaf(v, v, qq); }
                    if (OUT16) Ch[(size_t)rowg * ldc + col] = (_Float16)v;
                    else       Cf[(size_t)rowg * ldc + col] = v;
                }
            }
            if (STATS) {
                ss += __shfl_down(ss, 32); ss += __shfl_down(ss, 16);
                qq += __shfl_down(qq, 32); qq += __shfl_down(qq, 16);
                if (lane < 16) {
                    atomicAdd(&sums[col], ss);
                    atomicAdd(&sqs[col], qq);
                }
            }
        }
    } else {
        _Float16* AsA = (_Float16*)SMraw;            // [2][64][64] pre-swizzled adjacency
        _Float16* Xs  = (_Float16*)(SMraw + 16384);  // [64 cols][128 rows] swizzled C^T
        const _Float16* Ag = Ahg + (size_t)(bm >> 6) * 4096;
        #pragma unroll
        for (int j = 0; j < 4; ++j)
            __builtin_amdgcn_global_load_lds(
                (const __attribute__((address_space(1))) void*)(Ag + wave * 2048 + j * 512 + lane * 8),
                (__attribute__((address_space(3))) void*)&AsA[wave * 2048 + j * 512], 16, 0, 0);
        #pragma unroll
        for (int n = 0; n < 2; ++n) {
            int c = wc * 32 + n * 16 + ocol;
            float bb = HASB ? bias[bn + c] : 0.f;
            int csw = (c & 7) << 3;
            #pragma unroll
            for (int m = 0; m < 4; ++m) {
                #pragma unroll
                for (int r = 0; r < 4; ++r) {
                    int srow = wr * 64 + m * 16 + orow0 + r;
                    Xs[c * 128 + (srow & 64) + ((srow & 63) ^ csw)] = (_Float16)(acc[m][n][r] + bb);
                }
            }
        }
        __syncthreads();
        const int gg = wave >> 1, rh = wave & 1;
        f32x4 acc2[2][4];
        #pragma unroll
        for (int m2 = 0; m2 < 2; ++m2)
            #pragma unroll
            for (int n2 = 0; n2 < 4; ++n2)
                acc2[m2][n2] = (f32x4){0.f, 0.f, 0.f, 0.f};
        #pragma unroll
        for (int kc = 0; kc < 2; ++kc) {
            int ko = (kc * 32 + kh) ^ sw;
            #pragma unroll
            for (int m2 = 0; m2 < 2; ++m2) {
                int arow = rh * 32 + m2 * 16 + fl;
                half8 av = *(const half8*)&AsA[gg * 4096 + arow * 64 + ko];
                #pragma unroll
                for (int n2 = 0; n2 < 4; ++n2) {
                    int c = n2 * 16 + fl;
                    half8 bv = *(const half8*)&Xs[c * 128 + gg * 64 + ((kc * 32 + kh) ^ ((c & 7) << 3))];
                    acc2[m2][n2] = __builtin_amdgcn_mfma_f32_16x16x32_f16(av, bv, acc2[m2][n2], 0, 0, 0);
                }
            }
        }
        __syncthreads();
        float* Cs = (float*)SMraw;   // [128][68]
        #pragma unroll
        for (int m2 = 0; m2 < 2; ++m2)
            #pragma unroll
            for (int n2 = 0; n2 < 4; ++n2)
                #pragma unroll
                for (int r = 0; r < 4; ++r)
                    Cs[(gg * 64 + rh * 32 + m2 * 16 + orow0 + r) * 68 + n2 * 16 + ocol] = acc2[m2][n2][r];
        __syncthreads();
        const int rr = tid >> 3, dq = tid & 7;
        #pragma unroll
        for (int pass = 0; pass < 4; ++pass) {
            int row = pass * 32 + rr;
            half8 hv;
            #pragma unroll
            for (int e = 0; e < 8; ++e) {
                float v = Cs[row * 68 + dq * 8 + e] + cb[bn + dq * 8 + e];
                v = v > 0.f ? v : 0.f;
                hv[e] = (_Float16)v;
            }
            *(half8*)(Zout + (size_t)(bm + row) * ZD + bn + dq * 8) = hv;
        }
        if (STATS && tid < 64) {
            float bb = cb[bn + tid];
            float ss = 0.f, qq = 0.f;
            for (int row = 0; row < 128; ++row) {
                float v = Cs[row * 68 + tid] + bb;
                v = v > 0.f ? v : 0.f;
                ss += v;
                qq = fmaf(v, v, qq);
            }
            atomicAdd(&sums[bn + tid], ss);
            atomicAdd(&sqs[bn + tid], qq);
        }
    }
}

// ---------------- per-graph Gram, split-K: grid (NG, 2) ----------------
__global__ __launch_bounds__(256)
void gram_mfma(const _Float16* __restrict__ Z, float* __restrict__ Gparts)
{
    __shared__ _Float16 Zs[4096];   // [64][64]
    const int g = blockIdx.x, khalf = blockIdx.y;
    const int tid = threadIdx.x;
    const int lane = tid & 63, wave = tid >> 6;
    const int fl = lane & 15, kh = (lane >> 4) * 8;
    const int sw = (fl & 7) << 3;
    float* G = Gparts + (size_t)khalf * NG * 4096;

    f32x4 acc[4];
    #pragma unroll
    for (int n = 0; n < 4; ++n) acc[n] = (f32x4){0.f, 0.f, 0.f, 0.f};

    for (int k0 = khalf * (ZD / 2); k0 < (khalf + 1) * (ZD / 2); k0 += 64) {
        #pragma unroll
        for (int j = 0; j < 2; ++j) {
            int d = wave * 1024 + j * 512 + lane * 8;
            int row = d >> 6, kk = d & 63;
            int sk = kk ^ ((row & 7) << 3);
            __builtin_amdgcn_global_load_lds(
                (const __attribute__((address_space(1))) void*)(Z + (size_t)(g * 64 + row) * ZD + k0 + sk),
                (__attribute__((address_space(3))) void*)&Zs[wave * 1024 + j * 512], 16, 0, 0);
        }
        __syncthreads();
        #pragma unroll
        for (int kc = 0; kc < 2; ++kc) {
            int ko = (kc * 32 + kh) ^ sw;
            half8 av = *(const half8*)&Zs[(wave * 16 + fl) * 64 + ko];
            #pragma unroll
            for (int n = 0; n < 4; ++n) {
                half8 bv = *(const half8*)&Zs[(n * 16 + fl) * 64 + ko];
                acc[n] = __builtin_amdgcn_mfma_f32_16x16x32_f16(av, bv, acc[n], 0, 0, 0);
            }
        }
        __syncthreads();
    }
    const int orow0 = (lane >> 4) * 4;
    const int ocol  = lane & 15;
    #pragma unroll
    for (int n = 0; n < 4; ++n)
        #pragma unroll
        for (int r = 0; r < 4; ++r)
            G[(size_t)(g * 64 + wave * 16 + orow0 + r) * 64 + n * 16 + ocol] = acc[n][r];
}

// ---------------- edge loss (both sets; G = G0 + G1), lrc_final fused (last block) ------
__global__ void edge_loss2(const int* __restrict__ ei, const int* __restrict__ nei,
                           const float* __restrict__ G0, float* __restrict__ LOSS,
                           unsigned int* __restrict__ ctr, float* __restrict__ outLrc)
{
    const int setid = blockIdx.y;
    const int* e0 = setid ? nei : ei;
    const int* e1 = e0 + NE;
    float* tot = LOSS + setid * 256;
    float* cnt = tot + 128;
    const float* G1 = G0 + (size_t)NG * 4096;
    __shared__ float lt[128];
    __shared__ float lc[128];
    __shared__ float red[128];
    __shared__ unsigned int lastS;
    int tid = threadIdx.x;
    if (tid < 128) { lt[tid] = 0.f; lc[tid] = 0.f; }
    __syncthreads();
    for (int e = blockIdx.x * blockDim.x + tid; e < NE; e += gridDim.x * blockDim.x) {
        int a = e0[e], b = e1[e];
        int g = a >> 6;
        size_t idx = (size_t)((g << 6) + (a & 63)) * 64 + (b & 63);
        float v = G0[idx] + G1[idx];
        float s = 1.f / (1.f + expf(-v));
        float p = setid ? (1.f - s) : s;
        float l = -logf(1e-4f + p);
        atomicAdd(&lt[g], l);
        atomicAdd(&lc[g], 1.f);
    }
    __syncthreads();
    if (tid < 128) {
        atomicAdd(&tot[tid], lt[tid]);
        atomicAdd(&cnt[tid], lc[tid]);
    }
    __threadfence();
    __syncthreads();
    if (tid == 0) lastS = atomicAdd(ctr, 1u);
    __syncthreads();
    if (lastS == gridDim.x * gridDim.y - 1) {
        __threadfence();
        if (tid < 128) {
            float v = LOSS[tid] / fmaxf(LOSS[128 + tid], 1.f) +
                      LOSS[256 + tid] / fmaxf(LOSS[384 + tid], 1.f);
            red[tid] = v;
        }
        __syncthreads();
        for (int s = 64; s; s >>= 1) {
            if (tid < s && tid + s < 128) red[tid] += red[tid + s];
            __syncthreads();
        }
        if (tid == 0) outLrc[0] = red[0] * (1.0f / 128.0f);
    }
}

// ---------------- fused featW-GEMM + attention: 128x64 tile (2 graphs), per (panel, head) ----
__global__ __launch_bounds__(256)
void featattn(const _Float16* __restrict__ Z, const _Float16* __restrict__ featWt,
              const float* __restrict__ phi, _Float16* __restrict__ agg)
{
    __shared__ __align__(16) char SMraw[68608];
    _Float16* As  = (_Float16*)SMraw;             // [128][64] Z tile (phase 1)
    _Float16* Bs  = (_Float16*)(SMraw + 16384);   // [64][64] featW tile (phase 1)
    float*    Cs  = (float*)SMraw;                // [128][68] f32 (phase 2)
    _Float16* Xt  = (_Float16*)(SMraw + 34816);   // [2][d][b] swizzled
    _Float16* Ws  = (_Float16*)(SMraw + 51200);   // [2][i][b] swizzled
    float*    s1s = (float*)(SMraw + 67584);      // 128
    float*    s2s = (float*)(SMraw + 68096);      // 128
    const int pnl = blockIdx.x, h = blockIdx.y;
    const int bm = pnl * 128;
    const int tid = threadIdx.x;
    const int lane = tid & 63, wave = tid >> 6;
    const int wr = wave >> 1, wc = wave & 1;
    const int fl = lane & 15, kh = (lane >> 4) * 8;
    const int sw = (fl & 7) << 3;

    f32x4 acc[4][2];
    #pragma unroll
    for (int m = 0; m < 4; ++m)
        #pragma unroll
        for (int n = 0; n < 2; ++n)
            acc[m][n] = (f32x4){0.f, 0.f, 0.f, 0.f};

    for (int k0 = 0; k0 < ZD; k0 += 64) {
        #pragma unroll
        for (int j = 0; j < 4; ++j) {
            int d = wave * 2048 + j * 512 + lane * 8;
            int row = d >> 6, kk = d & 63;
            int sk = kk ^ ((row & 7) << 3);
            __builtin_amdgcn_global_load_lds(
                (const __attribute__((address_space(1))) void*)(Z + (size_t)(bm + row) * ZD + k0 + sk),
                (__attribute__((address_space(3))) void*)&As[wave * 2048 + j * 512], 16, 0, 0);
        }
        #pragma unroll
        for (int j = 0; j < 2; ++j) {
            int d = wave * 1024 + j * 512 + lane * 8;
            int row = d >> 6, kk = d & 63;
            int sk = kk ^ ((row & 7) << 3);
            __builtin_amdgcn_global_load_lds(
                (const __attribute__((address_space(1))) void*)(featWt + (size_t)(h * 64 + row) * ZD + k0 + sk),
                (__attribute__((address_space(3))) void*)&Bs[wave * 1024 + j * 512], 16, 0, 0);
        }
        __syncthreads();
        #pragma unroll
        for (int kc = 0; kc < 2; ++kc) {
            int ko = (kc * 32 + kh) ^ sw;
            half8 av[4], bv[2];
            #pragma unroll
            for (int m = 0; m < 4; ++m)
                av[m] = *(const half8*)&As[(wr * 64 + m * 16 + fl) * 64 + ko];
            #pragma unroll
            for (int n = 0; n < 2; ++n)
                bv[n] = *(const half8*)&Bs[(wc * 32 + n * 16 + fl) * 64 + ko];
            #pragma unroll
            for (int m = 0; m < 4; ++m)
                #pragma unroll
                for (int n = 0; n < 2; ++n)
                    acc[m][n] = __builtin_amdgcn_mfma_f32_16x16x32_f16(av[m], bv[n], acc[m][n], 0, 0, 0);
        }
        __syncthreads();
    }
    const int orow0 = (lane >> 4) * 4, ocol = lane & 15;
    #pragma unroll
    for (int n = 0; n < 2; ++n) {
        int col = wc * 32 + n * 16 + ocol;
        #pragma unroll
        for (int m = 0; m < 4; ++m)
            #pragma unroll
            for (int r = 0; r < 4; ++r)
                Cs[(wr * 64 + m * 16 + orow0 + r) * 68 + col] = acc[m][n][r];
    }
    __syncthreads();
    {
        const int bnode = tid >> 1, dq = tid & 1;
        const int gg = bnode >> 6, bloc = bnode & 63;
        const float* pa = phi + h * 128 + dq * 32;
        const float* pb = pa + 64;
        float sa = 0.f, sb = 0.f;
        #pragma unroll
        for (int j = 0; j < 32; ++j) {
            int d = dq * 32 + j;
            float vf = Cs[bnode * 68 + d];
            Xt[gg * 4096 + ((d * 64 + bloc) ^ ((d & 7) << 3))] = (_Float16)vf;
            sa = fmaf(vf, pa[j], sa);
            sb = fmaf(vf, pb[j], sb);
        }
        sa += __shfl_down(sa, 1);
        sb += __shfl_down(sb, 1);
        if (dq == 0) { s1s[bnode] = sa; s2s[bnode] = sb; }
    }
    __syncthreads();
    {
        const int inode = tid >> 1, bq = tid & 1;
        const int gg = inode >> 6, iloc = inode & 63;
        float si = s1s[inode];
        #pragma unroll
        for (int e = 0; e < 32; ++e) {
            int b = bq * 32 + e;
            float t = si + s2s[gg * 64 + b];
            t = t > 0.f ? t : 0.01f * t;
            float w = 1.f / (1.f + expf(-t));
            Ws[gg * 4096 + ((iloc * 64 + b) ^ ((iloc & 7) << 3))] = (_Float16)w;
        }
    }
    __syncthreads();
    const int gg = wave >> 1, rh = wave & 1;
    f32x4 acc2[2][4];
    #pragma unroll
    for (int m2 = 0; m2 < 2; ++m2)
        #pragma unroll
        for (int n2 = 0; n2 < 4; ++n2)
            acc2[m2][n2] = (f32x4){0.f, 0.f, 0.f, 0.f};
    #pragma unroll
    for (int kc = 0; kc < 2; ++kc) {
        #pragma unroll
        for (int m2 = 0; m2 < 2; ++m2) {
            int arow = rh * 32 + m2 * 16 + fl;
            half8 av = *(const half8*)&Ws[gg * 4096 + ((arow * 64 + kc * 32 + kh) ^ ((arow & 7) << 3))];
            #pragma unroll
            for (int n2 = 0; n2 < 4; ++n2) {
                int rowb = n2 * 16 + fl;
                half8 bv = *(const half8*)&Xt[gg * 4096 + ((rowb * 64 + kc * 32 + kh) ^ ((rowb & 7) << 3))];
                acc2[m2][n2] = __builtin_amdgcn_mfma_f32_16x16x32_f16(av, bv, acc2[m2][n2], 0, 0, 0);
            }
        }
    }
    __syncthreads();
    #pragma unroll
    for (int m2 = 0; m2 < 2; ++m2)
        #pragma unroll
        for (int n2 = 0; n2 < 4; ++n2)
            #pragma unroll
            for (int r = 0; r < 4; ++r)
                Cs[(gg * 64 + rh * 32 + m2 * 16 + orow0 + r) * 68 + n2 * 16 + ocol] = acc2[m2][n2][r];
    __syncthreads();
    {
        const int rr = tid >> 3, dq = tid & 7;
        #pragma unroll
        for (int pass = 0; pass < 4; ++pass) {
            int row = pass * 32 + rr;
            half8 hv;
            #pragma unroll
            for (int e = 0; e < 8; ++e)
                hv[e] = (_Float16)Cs[row * 68 + dq * 8 + e];
            *(half8*)(agg + (size_t)(bm + row) * CL + h * 64 + dq * 8) = hv;
        }
    }
}

// ---------------- fused fc1 + head + per-graph mean, per graph ----------------
__global__ __launch_bounds__(256)
void fc1head(const _Float16* __restrict__ AGG, const _Float16* __restrict__ fc1Wt,
             const float* __restrict__ fc1b,
             const float* __restrict__ fc2W, const float* __restrict__ fc2b,
             float* __restrict__ preds, float* __restrict__ outlog)
{
    __shared__ __align__(16) char SMraw[17664];
    _Float16* As = (_Float16*)SMraw;              // [64][64]
    _Float16* Bs = (_Float16*)(SMraw + 8192);     // [64][64]
    float*    Cs = (float*)SMraw;                 // [64][69] f32 hid
    const int g = blockIdx.x;
    const int tid = threadIdx.x;
    const int lane = tid & 63, wave = tid >> 6;
    const int fl = lane & 15, kh = (lane >> 4) * 8;
    const int sw = (fl & 7) << 3;

    f32x4 acc[4];
    #pragma unroll
    for (int n = 0; n < 4; ++n) acc[n] = (f32x4){0.f, 0.f, 0.f, 0.f};

    for (int k0 = 0; k0 < CL; k0 += 64) {
        #pragma unroll
        for (int j = 0; j < 2; ++j) {
            int d = wave * 1024 + j * 512 + lane * 8;
            int row = d >> 6, kk = d & 63;
            int sk = kk ^ ((row & 7) << 3);
            __builtin_amdgcn_global_load_lds(
                (const __attribute__((address_space(1))) void*)(AGG + (size_t)(g * 64 + row) * CL + k0 + sk),
                (__attribute__((address_space(3))) void*)&As[wave * 1024 + j * 512], 16, 0, 0);
            __builtin_amdgcn_global_load_lds(
                (const __attribute__((address_space(1))) void*)(fc1Wt + (size_t)row * CL + k0 + sk),
                (__attribute__((address_space(3))) void*)&Bs[wave * 1024 + j * 512], 16, 0, 0);
        }
        __syncthreads();
        #pragma unroll
        for (int kc = 0; kc < 2; ++kc) {
            int ko = (kc * 32 + kh) ^ sw;
            half8 av = *(const half8*)&As[(wave * 16 + fl) * 64 + ko];
            #pragma unroll
            for (int n = 0; n < 4; ++n) {
                half8 bv = *(const half8*)&Bs[(n * 16 + fl) * 64 + ko];
                acc[n] = __builtin_amdgcn_mfma_f32_16x16x32_f16(av, bv, acc[n], 0, 0, 0);
            }
        }
        __syncthreads();
    }
    const int orow0 = (lane >> 4) * 4, ocol = lane & 15;
    #pragma unroll
    for (int n = 0; n < 4; ++n) {
        int col = n * 16 + ocol;
        float bb = fc1b[col];
        #pragma unroll
        for (int r = 0; r < 4; ++r) {
            float v = acc[n][r] + bb;
            v = v > 0.f ? v : 0.01f * v;
            Cs[(wave * 16 + orow0 + r) * 69 + col] = v;
        }
    }
    __syncthreads();
    if (tid < 64) {
        float lg[10];
        float mx = -1e30f;
        #pragma unroll
        for (int c = 0; c < 10; ++c) {
            float s = fc2b[c];
            #pragma unroll
            for (int k = 0; k < 64; ++k) s = fmaf(Cs[tid * 69 + k], fc2W[k * 10 + c], s);
            lg[c] = s;
            mx = fmaxf(mx, s);
        }
        float sum = 0.f;
        #pragma unroll
        for (int c = 0; c < 10; ++c) {
            float t = expf(lg[c] - mx) + 1e-4f;
            lg[c] = t;
            sum += t;
        }
        float inv = 1.f / sum;
        #pragma unroll
        for (int c = 0; c < 10; ++c) {
            lg[c] *= inv;
            preds[(size_t)(g * 64 + tid) * 10 + c] = lg[c];
        }
        #pragma unroll
        for (int off = 32; off; off >>= 1)
            #pragma unroll
            for (int c = 0; c < 10; ++c) lg[c] += __shfl_down(lg[c], off);
        if (tid == 0)
            #pragma unroll
            for (int c = 0; c < 10; ++c) outlog[g * 10 + c] = logf(lg[c] * (1.0f / 64.0f));
    }
}

extern "C" void kernel_launch(void* const* d_in, const int* in_sizes, int n_in,
                              void* d_out, int out_size, void* d_ws, size_t ws_size,
                              hipStream_t stream)
{
    (void)in_sizes; (void)n_in; (void)out_size; (void)ws_size;
    const float* x     = (const float*)d_in[0];
    const int*   ei    = (const int*)d_in[1];
    const int*   nei   = (const int*)d_in[2];
    const float* fcW   = (const float*)d_in[5];
    const float* fcb   = (const float*)d_in[6];
    const float* bng   = (const float*)d_in[7];
    const float* bnb   = (const float*)d_in[8];
    const float* convW = (const float*)d_in[9];
    const float* convb = (const float*)d_in[10];
    const float* featW = (const float*)d_in[11];
    const float* phi   = (const float*)d_in[12];
    const float* fc1W  = (const float*)d_in[13];
    const float* fc1b  = (const float*)d_in[14];
    const float* fc2W  = (const float*)d_in[15];
    const float* fc2b  = (const float*)d_in[16];
    float* out = (float*)d_out;

    char* ws = (char*)d_ws;
    _Float16* Z       = (_Float16*)(ws);              // 24 MB  -> 25165824
    _Float16* H0      = (_Float16*)(ws + 25165824);   // 8 MB   -> 33554432
    _Float16* AGG     = (_Float16*)(ws + 33554432);   // 8 MB   -> 41943040
    _Float16* xb      = (_Float16*)(ws + 41943040);   // 2 MB   -> 44040192
    _Float16* fcWt    = (_Float16*)(ws + 44040192);   // 128 KB -> 44171264
    _Float16* convWs  = (_Float16*)(ws + 44171264);   // 512 KB -> 44695552
    _Float16* featWt  = (_Float16*)(ws + 44695552);   // 1.5 MB -> 46268416
    _Float16* fc1Wt   = (_Float16*)(ws + 46268416);   // 64 KB  -> 46333952
    _Float16* Ah      = (_Float16*)(ws + 46333952);   // 1 MB   -> 47382528
    float*    Gram    = (float*)(ws + 47382528);      // 4 MB (2 parts) -> 51576832
    // zeroed region: Acnt + LOSS + BNS3 + B2x3 + CTR
    float*    Acnt    = (float*)(ws + 51576832);      // 2 MB   -> 53673984
    float*    LOSS    = (float*)(ws + 53673984);      // 2 KB   -> 53676032
    float*    BNS3    = (float*)(ws + 53676032);      // 12 KB  -> 53688320
    float*    B2      = (float*)(ws + 53688320);      // 6 KB   -> 53694464
    unsigned int* CTR = (unsigned int*)(ws + 53694464); // 256 B -> 53694720

    hipMemsetAsync(Acnt, 0, 53694720 - 51576832, stream);

    // consolidated prep: cvt_h + 3x weight transpose + edge-count atomics
    prep_misc<<<2400, 256, 0, stream>>>(x, xb, fcW, fcWt, featW, featWt,
                                        fc1W, fc1Wt, ei, Acnt);
    // counts -> normalized f16 pre-swizzled adjacency (deg from row-sums, diag folded)
    finalize_adj<<<NG, 256, 0, stream>>>(Acnt, Ah);

    // h0 = x @ fc_W + fc_b  (f16 out, layer-0 BN stats fused)
    gemm_f16<0, true, true, true, false><<<dim3(CL / 64, NN / 128), 256, 0, stream>>>(
        xb, NF, fcWt, NF, nullptr, H0, CL, fcb, NF, BNS3, BNS3 + 512,
        nullptr, nullptr, nullptr);

    for (int i = 0; i < 3; ++i) {
        const _Float16* Ain = (i == 0) ? H0 : (Z + (size_t)(i - 1) * CL);
        int lda = (i == 0) ? CL : ZD;
        float* sums = BNS3 + i * 1024;
        float* sqs  = sums + 512;
        float* b2   = B2 + i * 512;
        wprep<<<dim3(CL / 32, CL / 32), dim3(32, 8), 0, stream>>>(
            convW + (size_t)i * CL * CL, sums, sqs, bng + i * CL, bnb + i * CL,
            convWs, b2, CL, CL);
        if (i < 2)
            gemm_f16<0, true, false, true, true><<<dim3(CL / 64, NN / 128), 256, 0, stream>>>(
                Ain, lda, convWs, CL, nullptr, nullptr, 0, b2, CL,
                BNS3 + (i + 1) * 1024, BNS3 + (i + 1) * 1024 + 512,
                Ah, convb + i * CL, Z + (size_t)i * CL);
        else
            gemm_f16<0, true, false, false, true><<<dim3(CL / 64, NN / 128), 256, 0, stream>>>(
                Ain, lda, convWs, CL, nullptr, nullptr, 0, b2, CL,
                nullptr, nullptr, Ah, convb + i * CL, Z + (size_t)i * CL);
    }

    // edge reconstruction loss via split-K per-graph Gram (lrc fused into edge_loss2)
    gram_mfma<<<dim3(NG, 2), 256, 0, stream>>>(Z, Gram);
    edge_loss2<<<dim3(128, 2), 256, 0, stream>>>(ei, nei, Gram, LOSS, CTR, out + 1280);

    // fused featW GEMM (128x64 tile, 2 graphs/block) + attention -> AGG (f16)
    featattn<<<dim3(64, 8), 256, 0, stream>>>(Z, featWt, phi, AGG);

    // fused fc1 + head + per-graph mean
    fc1head<<<NG, 256, 0, stream>>>(AGG, fc1Wt, fc1b, fc2W, fc2b, out + 1281, out);
}